// Round 2
// baseline (1731.082 us; speedup 1.0000x reference)
//
#include <hip/hip_runtime.h>
#include <math.h>

typedef unsigned int u32;
typedef unsigned short u16;
typedef short s16x8 __attribute__((ext_vector_type(8)));
typedef float f32x4 __attribute__((ext_vector_type(4)));
typedef u16 u16x4 __attribute__((ext_vector_type(4)));
typedef u16 u16x8 __attribute__((ext_vector_type(8)));

#define B_  16
#define S_  2048
#define D_  1024
#define H_  256
#define SD_ 14
#define C_  6
#define G_  3
#define E_  18

static __device__ __forceinline__ u16 f2bf(float f) {
  u32 x = __builtin_bit_cast(u32, f);
  return (u16)((x + 0x7fffu + ((x >> 16) & 1u)) >> 16);
}

// ---------------- K3: convert features f32->bf16 + column-mean pooling ----------------
__global__ __launch_bounds__(256) void k_convpool(const float* __restrict__ F,
                                                  u16* __restrict__ Fbf,
                                                  float* __restrict__ fsum) {
  const int bb = blockIdx.x >> 5;   // batch 0..15
  const int sc = blockIdx.x & 31;   // 64-row chunk 0..31
  const int t  = threadIdx.x;       // 0..255, each owns 4 columns
  const size_t base = (size_t)(bb * S_ + sc * 64) * D_ + t * 4;
  float s0 = 0.f, s1 = 0.f, s2 = 0.f, s3 = 0.f;
  for (int i = 0; i < 64; ++i) {
    const f32x4 v = *(const f32x4*)(F + base + (size_t)i * D_);
    s0 += v[0]; s1 += v[1]; s2 += v[2]; s3 += v[3];
    u16x4 h;
    h[0] = f2bf(v[0]); h[1] = f2bf(v[1]); h[2] = f2bf(v[2]); h[3] = f2bf(v[3]);
    *(u16x4*)(Fbf + base + (size_t)i * D_) = h;
  }
  const int c = t * 4;
  atomicAdd(&fsum[bb * D_ + c + 0], s0);
  atomicAdd(&fsum[bb * D_ + c + 1], s1);
  atomicAdd(&fsum[bb * D_ + c + 2], s2);
  atomicAdd(&fsum[bb * D_ + c + 3], s3);
}

// ---------------- K3b: pooling only (lean path, no bf16 cache write) ----------------
__global__ __launch_bounds__(256) void k_poolF(const float* __restrict__ F,
                                               float* __restrict__ fsum) {
  const int bb = blockIdx.x >> 5;
  const int sc = blockIdx.x & 31;
  const int t  = threadIdx.x;
  const size_t base = (size_t)(bb * S_ + sc * 64) * D_ + t * 4;
  float s0 = 0.f, s1 = 0.f, s2 = 0.f, s3 = 0.f;
  for (int i = 0; i < 64; ++i) {
    const f32x4 v = *(const f32x4*)(F + base + (size_t)i * D_);
    s0 += v[0]; s1 += v[1]; s2 += v[2]; s3 += v[3];
  }
  const int c = t * 4;
  atomicAdd(&fsum[bb * D_ + c + 0], s0);
  atomicAdd(&fsum[bb * D_ + c + 1], s1);
  atomicAdd(&fsum[bb * D_ + c + 2], s2);
  atomicAdd(&fsum[bb * D_ + c + 3], s3);
}

// ---------------- K1: x_raw column-mean pooling ----------------
__global__ __launch_bounds__(256) void k_xpool(const float* __restrict__ X,
                                               float* __restrict__ xsum) {
  const int b = blockIdx.x;
  const int t = threadIdx.x;
  float ls[SD_];
  #pragma unroll
  for (int c = 0; c < SD_; ++c) ls[c] = 0.f;
  for (int s = t; s < S_; s += 256) {
    const float* row = X + (size_t)(b * S_ + s) * SD_;
    #pragma unroll
    for (int c = 0; c < SD_; ++c) ls[c] += row[c];
  }
  #pragma unroll
  for (int c = 0; c < SD_; ++c) atomicAdd(&xsum[b * SD_ + c], ls[c]);
}

// ---------------- K2: routers + flat weights + expert loads + lb + bias term ----------------
__global__ __launch_bounds__(256) void k_router(const float* __restrict__ fsum,
                                                const float* __restrict__ xsum,
                                                const float* __restrict__ cond_w,
                                                const float* __restrict__ cond_b,
                                                const float* __restrict__ stage_w,
                                                const float* __restrict__ stage_b,
                                                const float* __restrict__ up_b,
                                                float* __restrict__ flatw,
                                                float* __restrict__ biasws,
                                                float* __restrict__ out_tail) {
  __shared__ float s_cl[B_][C_], s_sl[B_][G_];
  __shared__ float s_cw[B_][C_], s_sw[B_][G_];
  __shared__ float s_fw[B_][E_], s_ld[E_];
  const int t = threadIdx.x;
  if (t < B_ * C_) {
    const int b = t / C_, c = t % C_;
    float a = cond_b[c];
    for (int d = 0; d < D_; ++d) a += (fsum[b * D_ + d] * (1.f / S_)) * cond_w[d * C_ + c];
    s_cl[b][c] = a;
  }
  if (t < B_ * G_) {
    const int b = t / G_, g = t % G_;
    float a = stage_b[g];
    for (int sd = 0; sd < SD_; ++sd) a += (xsum[b * SD_ + sd] * (1.f / S_)) * stage_w[sd * G_ + g];
    s_sl[b][g] = a;
  }
  __syncthreads();
  if (t < B_) {
    float m = s_cl[t][0];
    for (int c = 1; c < C_; ++c) m = fmaxf(m, s_cl[t][c]);
    float den = 0.f, ex[C_];
    for (int c = 0; c < C_; ++c) { ex[c] = expf(s_cl[t][c] - m); den += ex[c]; }
    for (int c = 0; c < C_; ++c) s_cw[t][c] = ex[c] / den;
    float m2 = s_sl[t][0];
    for (int g = 1; g < G_; ++g) m2 = fmaxf(m2, s_sl[t][g]);
    float den2 = 0.f, ex2[G_];
    for (int g = 0; g < G_; ++g) { ex2[g] = expf(s_sl[t][g] - m2); den2 += ex2[g]; }
    for (int g = 0; g < G_; ++g) s_sw[t][g] = ex2[g] / den2;
    for (int c = 0; c < C_; ++c)
      for (int g = 0; g < G_; ++g) s_fw[t][c * G_ + g] = s_cw[t][c] * s_sw[t][g];
  }
  __syncthreads();
  if (t < B_ * C_) out_tail[t] = s_cw[t / C_][t % C_];
  if (t < B_ * G_) out_tail[B_ * C_ + t] = s_sw[t / G_][t % G_];
  // B_*E_ = 288 > 256 threads: MUST be a strided loop (round-1 bug: entries
  // 256..287 i.e. batches 14-15 were never written -> their delta vanished).
  for (int i = t; i < B_ * E_; i += 256) flatw[i] = s_fw[i / E_][i % E_];
  if (t < E_) {
    float a = 0.f;
    for (int b = 0; b < B_; ++b) a += s_fw[b][t];
    s_ld[t] = a / (float)B_;
    out_tail[B_ * C_ + B_ * G_ + t] = s_ld[t];
  }
  __syncthreads();
  if (t == 0) {
    float a = 0.f;
    for (int e = 0; e < E_; ++e) a += s_ld[e] * s_ld[e];
    out_tail[B_ * C_ + B_ * G_ + E_] = (float)E_ * a * 0.01f;
  }
  for (int i = t; i < B_ * D_; i += 256) {
    const int b = i >> 10, d = i & 1023;
    float a = 0.f;
    #pragma unroll
    for (int e = 0; e < E_; ++e) a += s_fw[b][e] * up_b[e * D_ + d];
    biasws[i] = a;
  }
}

// ---------------- K4: [E][Rr][Cc] f32 -> [E][Cc][Rr] bf16 transpose ----------------
__global__ __launch_bounds__(256) void k_transpose(const float* __restrict__ src,
                                                   u16* __restrict__ dst, int Rr, int Cc) {
  const int tiles_c = Cc >> 6, tiles_r = Rr >> 6;
  const int id = blockIdx.x;
  const int e = id / (tiles_r * tiles_c);
  const int rem = id % (tiles_r * tiles_c);
  const int r0 = (rem / tiles_c) << 6, c0 = (rem % tiles_c) << 6;
  __shared__ float tile[64][65];
  const int t = threadIdx.x;
  const float* sp = src + (size_t)e * Rr * Cc;
  #pragma unroll
  for (int i = 0; i < 4; ++i) {
    const int lin = i * 1024 + t * 4;
    const int r = lin >> 6, c = lin & 63;
    const f32x4 v = *(const f32x4*)(sp + (size_t)(r0 + r) * Cc + c0 + c);
    tile[r][c] = v[0]; tile[r][c + 1] = v[1]; tile[r][c + 2] = v[2]; tile[r][c + 3] = v[3];
  }
  __syncthreads();
  u16* dp = dst + (size_t)e * Rr * Cc;
  #pragma unroll
  for (int i = 0; i < 4; ++i) {
    const int lin = i * 1024 + t * 4;
    const int cr = lin >> 6, rc = lin & 63;
    u16x4 h;
    h[0] = f2bf(tile[rc + 0][cr]);
    h[1] = f2bf(tile[rc + 1][cr]);
    h[2] = f2bf(tile[rc + 2][cr]);
    h[3] = f2bf(tile[rc + 3][cr]);
    *(u16x4*)(dp + (size_t)(c0 + cr) * Rr + r0 + rc) = h;
  }
}

// ---------------- K5: fused MoE main kernel ----------------
// tile = 64 rows of (b,s), full D=1024 output. 8 waves; wave w owns output cols
// [w*128, w*128+128) in UP phase and h-cols [w*32, w*32+32) in DOWN phase.
template<int LEAN>
__global__ __launch_bounds__(512, 2) void k_moe(const u16* __restrict__ Fbf,
                                                const float* __restrict__ Ff32,
                                                const u16* __restrict__ dwT,   // [E][H][D] bf16
                                                const u16* __restrict__ uwT,   // [E][D][H] bf16
                                                const float* __restrict__ down_b,
                                                const float* __restrict__ flatw,
                                                const float* __restrict__ biasws,
                                                float* __restrict__ out) {
  __shared__ u16 Fb[64 * 1024];  // 128 KiB, row stride 2048B, XOR-swizzled 16B slots
  __shared__ u16 Hb[64 * 256];   // 32 KiB, row stride 512B, XOR-swizzled

  const int tile = blockIdx.x;
  const int r0 = tile * 64;
  const int b = r0 >> 11;
  const int t = threadIdx.x;
  const int w = t >> 6;
  const int l = t & 63;
  const int l15 = l & 15;
  const int lhi = l >> 4;
  const int sw7 = (l & 7) << 4;  // (row&7)<<4 for rows of form l15+16*fr

  // ---- stage F tile (once, reused by all 18 experts) ----
  #pragma unroll
  for (int i = 0; i < 16; ++i) {
    const int slot = i * 512 + t;   // 16B slots
    const int row = slot >> 7;      // 0..63
    const int isl = slot & 127;     // slot within row
    char* dst = (char*)Fb + row * 2048 + ((isl * 16) ^ ((row & 7) << 4));
    if constexpr (!LEAN) {
      *(u16x8*)dst = *(const u16x8*)(Fbf + (size_t)(r0 + row) * D_ + isl * 8);
    } else {
      const float* src = Ff32 + (size_t)(r0 + row) * D_ + isl * 8;
      const f32x4 v0 = *(const f32x4*)src;
      const f32x4 v1 = *(const f32x4*)(src + 4);
      u16x8 h;
      h[0] = f2bf(v0[0]); h[1] = f2bf(v0[1]); h[2] = f2bf(v0[2]); h[3] = f2bf(v0[3]);
      h[4] = f2bf(v1[0]); h[5] = f2bf(v1[1]); h[6] = f2bf(v1[2]); h[7] = f2bf(v1[3]);
      *(u16x8*)dst = h;
    }
  }

  f32x4 acc[4][8];
  #pragma unroll
  for (int i = 0; i < 4; ++i)
    #pragma unroll
    for (int j = 0; j < 8; ++j)
      acc[i][j] = f32x4{0.f, 0.f, 0.f, 0.f};

  __syncthreads();

  const float* fwb = flatw + b * E_;

  for (int e = 0; e < E_; ++e) {
    // ---- DOWN: h[64 x 32cols/wave] = F(64x1024) @ dw[e], B-frags direct from global dwT ----
    const u16* dwe = dwT + (size_t)e * (H_ * D_);
    const u16* brow0 = dwe + (size_t)(w * 32 + l15) * D_ + lhi * 8;
    const u16* brow1 = brow0 + (size_t)16 * D_;
    f32x4 hacc[4][2];
    #pragma unroll
    for (int fr = 0; fr < 4; ++fr) {
      hacc[fr][0] = f32x4{0.f, 0.f, 0.f, 0.f};
      hacc[fr][1] = f32x4{0.f, 0.f, 0.f, 0.f};
    }
    #pragma unroll
    for (int kk = 0; kk < 32; ++kk) {
      const s16x8 b0 = *(const s16x8*)(brow0 + kk * 32);
      const s16x8 b1 = *(const s16x8*)(brow1 + kk * 32);
      const int kb = kk * 64;
      #pragma unroll
      for (int fr = 0; fr < 4; ++fr) {
        const int row = l15 + fr * 16;
        const s16x8 a = *(const s16x8*)((const char*)Fb + row * 2048 + ((kb + lhi * 16) ^ sw7));
        hacc[fr][0] = __builtin_amdgcn_mfma_f32_16x16x32_bf16(a, b0, hacc[fr][0], 0, 0, 0);
        hacc[fr][1] = __builtin_amdgcn_mfma_f32_16x16x32_bf16(a, b1, hacc[fr][1], 0, 0, 0);
      }
    }
    __syncthreads();  // previous expert's up-phase reads of Hb complete
    // ---- gelu (exact erf) + routing-weight scale -> Hb ----
    const float wbe = fwb[e];
    #pragma unroll
    for (int fc = 0; fc < 2; ++fc) {
      const int hc = w * 32 + fc * 16 + l15;
      const float dbv = down_b[e * H_ + hc];
      #pragma unroll
      for (int fr = 0; fr < 4; ++fr) {
        #pragma unroll
        for (int i = 0; i < 4; ++i) {
          const int row = fr * 16 + lhi * 4 + i;
          const float x = hacc[fr][fc][i] + dbv;
          const float g = 0.5f * x * (1.f + erff(x * 0.70710678f));
          *(u16*)((char*)Hb + row * 512 + ((hc * 2) ^ ((row & 7) << 4))) = f2bf(g * wbe);
        }
      }
    }
    __syncthreads();
    // ---- UP: acc[64 x 128cols/wave] += Hb(64x256) @ uw[e], B-frags direct from global uwT ----
    const u16* uwe = uwT + (size_t)e * (D_ * H_) + (size_t)(w * 128 + l15) * H_ + lhi * 8;
    #pragma unroll
    for (int ks = 0; ks < 8; ++ks) {
      s16x8 a[4];
      #pragma unroll
      for (int fr = 0; fr < 4; ++fr) {
        const int row = l15 + fr * 16;
        a[fr] = *(const s16x8*)((const char*)Hb + row * 512 + ((ks * 64 + lhi * 16) ^ sw7));
      }
      #pragma unroll
      for (int fc = 0; fc < 8; ++fc) {
        const s16x8 bb = *(const s16x8*)(uwe + (size_t)(fc * 16) * H_ + ks * 32);
        #pragma unroll
        for (int fr = 0; fr < 4; ++fr)
          acc[fr][fc] = __builtin_amdgcn_mfma_f32_16x16x32_bf16(a[fr], bb, acc[fr][fc], 0, 0, 0);
      }
    }
  }

  // ---- epilogue: residual (f32 features) + bias term + store ----
  const float* bias = biasws + b * D_;
  #pragma unroll
  for (int fc = 0; fc < 8; ++fc) {
    const int col = w * 128 + fc * 16 + l15;
    const float bv = bias[col];
    #pragma unroll
    for (int fr = 0; fr < 4; ++fr) {
      #pragma unroll
      for (int i = 0; i < 4; ++i) {
        const int row = fr * 16 + lhi * 4 + i;
        const size_t idx = (size_t)(r0 + row) * D_ + col;
        out[idx] = acc[fr][fc][i] + Ff32[idx] + bv;
      }
    }
  }
}

extern "C" void kernel_launch(void* const* d_in, const int* in_sizes, int n_in,
                              void* d_out, int out_size, void* d_ws, size_t ws_size,
                              hipStream_t stream) {
  const float* F  = (const float*)d_in[0];
  const float* X  = (const float*)d_in[1];
  const float* dw = (const float*)d_in[2];
  const float* db = (const float*)d_in[3];
  const float* uw = (const float*)d_in[4];
  const float* ub = (const float*)d_in[5];
  const float* cw = (const float*)d_in[6];
  const float* cb = (const float*)d_in[7];
  const float* sw = (const float*)d_in[8];
  const float* sb = (const float*)d_in[9];
  float* out = (float*)d_out;

  char* ws = (char*)d_ws;
  float* fsum  = (float*)ws;                 // B*D
  float* xsum  = fsum + B_ * D_;             // B*SD
  float* flatw = xsum + B_ * SD_;            // B*E
  float* biasws = flatw + B_ * E_;           // B*D
  size_t off = (size_t)(B_ * D_ + B_ * SD_ + B_ * E_ + B_ * D_) * 4;
  off = (off + 255) & ~(size_t)255;
  u16* dwT = (u16*)(ws + off); off += (size_t)E_ * H_ * D_ * 2;
  u16* uwT = (u16*)(ws + off); off += (size_t)E_ * D_ * H_ * 2;
  const size_t need_lean = off;
  u16* Fbf = (u16*)(ws + off); off += (size_t)B_ * S_ * D_ * 2;
  const size_t need_full = off;

  if (ws_size < need_lean) return;  // cannot run; fail loudly at validation
  const bool lean = ws_size < need_full;

  hipMemsetAsync(d_ws, 0, (size_t)(B_ * D_ + B_ * SD_) * sizeof(float), stream);
  k_transpose<<<E_ * 16 * 4, 256, 0, stream>>>(dw, dwT, D_, H_);  // dw [E][D][H] -> dwT [E][H][D]
  k_transpose<<<E_ * 4 * 16, 256, 0, stream>>>(uw, uwT, H_, D_);  // uw [E][H][D] -> uwT [E][D][H]
  if (!lean) {
    k_convpool<<<512, 256, 0, stream>>>(F, Fbf, fsum);
  } else {
    k_poolF<<<512, 256, 0, stream>>>(F, fsum);
  }
  k_xpool<<<B_, 256, 0, stream>>>(X, xsum);
  k_router<<<1, 256, 0, stream>>>(fsum, xsum, cw, cb, sw, sb, ub, flatw, biasws,
                                  out + (size_t)B_ * S_ * D_);
  if (!lean) {
    k_moe<0><<<512, 512, 0, stream>>>(Fbf, F, dwT, uwT, db, flatw, biasws, out);
  } else {
    k_moe<1><<<512, 512, 0, stream>>>(nullptr, F, dwT, uwT, db, flatw, biasws, out);
  }
}